// Round 7
// baseline (551.968 us; speedup 1.0000x reference)
//
#include <hip/hip_runtime.h>

// RhythmNetLoss: out = mean(|r - t|) + 100 * mean(|g - mean(g)|)
// Inputs: 3x float32 [4096,4096]. Output: 1x float32 scalar.
//
// R6 lesson: cooperative grid.sync() = 14.7 MB of cross-XCD barrier spin
// traffic, 686us. Reverted. New structure: 2 dispatches with last-block-done
// reduction (1 int atomic per block):
//   kernel A: sum(g) (64 MB, L3-hot from harness restore) -> m
//   kernel B: single pass over r,t,g -> sum|r-t| AND sum|g-m| -> out
//
// ws layout: bytes [0..4) counterA, [4..8) counterB (memset 0 per launch);
// double idx 8 = m; double idx 16.. = partials A; then partials B (two arrays).

typedef float f32x4 __attribute__((ext_vector_type(4)));

#define LAMBD 100.0
#define BLOCK 256
#define PT 4
#define TILE (BLOCK * PT)     // 1024 float4 = 16 KiB per stream per tile

__device__ __forceinline__ int swizzle_tile(int tile, int ntiles) {
    if ((ntiles & 7) == 0) {           // bijective XCD swizzle
        int nx = ntiles >> 3;
        return (tile & 7) * nx + (tile >> 3);
    }
    return tile;
}

__global__ void __launch_bounds__(BLOCK) sumg_kernel(const f32x4* __restrict__ g,
                                                     double* __restrict__ wsd,
                                                     int* __restrict__ cnt,
                                                     int n4, int ntiles, double inv_n) {
    __shared__ float lf[4];
    __shared__ double ld[4];
    __shared__ int isLast;
    const int tid = threadIdx.x;

    int tile = swizzle_tile(blockIdx.x, ntiles);
    long base = (long)tile * TILE + tid;
    float s = 0.f;
    if ((long)tile * TILE + TILE <= n4) {
        f32x4 v[PT];
        #pragma unroll
        for (int k = 0; k < PT; ++k) v[k] = g[base + k * BLOCK];
        #pragma unroll
        for (int k = 0; k < PT; ++k) s += (v[k].x + v[k].y) + (v[k].z + v[k].w);
    } else {
        for (int k = 0; k < PT; ++k) {
            long i = base + (long)k * BLOCK;
            if (i < n4) { f32x4 v = g[i]; s += (v.x + v.y) + (v.z + v.w); }
        }
    }
    #pragma unroll
    for (int off = 32; off; off >>= 1) s += __shfl_down(s, off);
    if ((tid & 63) == 0) lf[tid >> 6] = s;
    __syncthreads();
    if (tid == 0) {
        wsd[16 + blockIdx.x] = (double)(lf[0] + lf[1] + lf[2] + lf[3]);
        __threadfence();                         // release partials (wbl2)
        int old = atomicAdd(cnt, 1);             // device-scope
        isLast = (old == (int)gridDim.x - 1);
    }
    __syncthreads();
    if (isLast) {
        __threadfence();                         // acquire (inv stale lines)
        double v = 0.0;
        for (int i = tid; i < (int)gridDim.x; i += BLOCK) v += wsd[16 + i];
        #pragma unroll
        for (int off = 32; off; off >>= 1) v += __shfl_down(v, off);
        if ((tid & 63) == 0) ld[tid >> 6] = v;
        __syncthreads();
        if (tid == 0) wsd[8] = (ld[0] + ld[1] + ld[2] + ld[3]) * inv_n;  // m
    }
}

__global__ void __launch_bounds__(BLOCK) main_kernel(const f32x4* __restrict__ r,
                                                     const f32x4* __restrict__ t,
                                                     const f32x4* __restrict__ g,
                                                     double* __restrict__ wsd,
                                                     int* __restrict__ cnt,
                                                     float* __restrict__ out,
                                                     int n4, int ntiles, double inv_n,
                                                     int p1, int p2) {
    __shared__ float lfa[4], lfb[4];
    __shared__ double lda[4], ldb[4];
    __shared__ int isLast;
    const int tid = threadIdx.x;
    const float m = (float)wsd[8];               // visible: dispatch boundary

    int tile = swizzle_tile(blockIdx.x, ntiles);
    long base = (long)tile * TILE + tid;
    float sa = 0.f, sd = 0.f;
    if ((long)tile * TILE + TILE <= n4) {
        f32x4 rv[PT], tv[PT], gv[PT];
        #pragma unroll
        for (int k = 0; k < PT; ++k) rv[k] = __builtin_nontemporal_load(&r[base + k * BLOCK]);
        #pragma unroll
        for (int k = 0; k < PT; ++k) tv[k] = __builtin_nontemporal_load(&t[base + k * BLOCK]);
        #pragma unroll
        for (int k = 0; k < PT; ++k) gv[k] = g[base + k * BLOCK];
        #pragma unroll
        for (int k = 0; k < PT; ++k) {
            f32x4 d = rv[k] - tv[k];
            sa += fabsf(d.x) + fabsf(d.y) + fabsf(d.z) + fabsf(d.w);
            sd += fabsf(gv[k].x - m) + fabsf(gv[k].y - m) +
                  fabsf(gv[k].z - m) + fabsf(gv[k].w - m);
        }
    } else {
        for (int k = 0; k < PT; ++k) {
            long i = base + (long)k * BLOCK;
            if (i < n4) {
                f32x4 rv = r[i], tv = t[i], gv = g[i];
                sa += fabsf(rv.x - tv.x) + fabsf(rv.y - tv.y) +
                      fabsf(rv.z - tv.z) + fabsf(rv.w - tv.w);
                sd += fabsf(gv.x - m) + fabsf(gv.y - m) +
                      fabsf(gv.z - m) + fabsf(gv.w - m);
            }
        }
    }
    #pragma unroll
    for (int off = 32; off; off >>= 1) {
        sa += __shfl_down(sa, off);
        sd += __shfl_down(sd, off);
    }
    if ((tid & 63) == 0) { lfa[tid >> 6] = sa; lfb[tid >> 6] = sd; }
    __syncthreads();
    if (tid == 0) {
        wsd[p1 + blockIdx.x] = (double)(lfa[0] + lfa[1] + lfa[2] + lfa[3]);
        wsd[p2 + blockIdx.x] = (double)(lfb[0] + lfb[1] + lfb[2] + lfb[3]);
        __threadfence();
        int old = atomicAdd(cnt, 1);
        isLast = (old == (int)gridDim.x - 1);
    }
    __syncthreads();
    if (isLast) {
        __threadfence();
        double a = 0.0, s = 0.0;
        for (int i = tid; i < (int)gridDim.x; i += BLOCK) {
            a += wsd[p1 + i];
            s += wsd[p2 + i];
        }
        #pragma unroll
        for (int off = 32; off; off >>= 1) {
            a += __shfl_down(a, off);
            s += __shfl_down(s, off);
        }
        if ((tid & 63) == 0) { lda[tid >> 6] = a; ldb[tid >> 6] = s; }
        __syncthreads();
        if (tid == 0) {
            double ra = lda[0] + lda[1] + lda[2] + lda[3];
            double rs = ldb[0] + ldb[1] + ldb[2] + ldb[3];
            out[0] = (float)(ra * inv_n + LAMBD * (rs * inv_n));
        }
    }
}

extern "C" void kernel_launch(void* const* d_in, const int* in_sizes, int n_in,
                              void* d_out, int out_size, void* d_ws, size_t ws_size,
                              hipStream_t stream) {
    const f32x4* r = (const f32x4*)d_in[0];
    const f32x4* g = (const f32x4*)d_in[1];
    const f32x4* t = (const f32x4*)d_in[2];
    float* out = (float*)d_out;
    double* wsd = (double*)d_ws;
    int* cntA = (int*)d_ws;
    int* cntB = cntA + 1;

    int n = in_sizes[0];                   // 16777216
    int n4 = n >> 2;                       // 4194304 float4s
    int ntiles = (n4 + TILE - 1) / TILE;   // 4096 (exact)
    double inv_n = 1.0 / (double)n;
    int p1 = 16 + ntiles;                  // double-index of sum|r-t| partials
    int p2 = p1 + ntiles;                  // double-index of sum|g-m| partials

    hipMemsetAsync(d_ws, 0, 2 * sizeof(int), stream);   // zero both counters

    sumg_kernel<<<ntiles, BLOCK, 0, stream>>>(g, wsd, cntA, n4, ntiles, inv_n);
    main_kernel<<<ntiles, BLOCK, 0, stream>>>(r, t, g, wsd, cntB, out,
                                              n4, ntiles, inv_n, p1, p2);
}